// Round 12
// baseline (30329.095 us; speedup 1.0000x reference)
//
#include <hip/hip_runtime.h>

// Pendulum 3-layer LSTM (H=128), B=256 rows, 1024 sequential steps.
// Head collapsed to y = weff.h3 + beff (exact fp32 precompute).
//
// ROUND 12: prefetch-distance fix. Round 9's 8.86us/step == (64 slots x
// ~325cy stall): 8-deep reg ring gives only ~175cy issue->use lead vs ~500cy
// L2 latency. Fix = double per-slot compute, not ring depth:
//   64 blocks x 512 threads x 4 ROWS/block. Thread = (idx 128, g2 2, kq 2):
//   owns 2 gates x K-half. Per slot: 16 fdot2 (~45cy) -> 7-slot lead ~600cy
//   wall >= latency. Gate-split halves accumulators (8/layer) so demand ~120
//   fits the 128-VGPR cap with NO spills (round 11 proved spills cost 1-2ms).
//   Cell update via quad shfl: xor1 = kq-reduce, xor2 = gate exchange, all
//   4 lanes compute redundantly. h reads are lane-uniform -> LDS broadcast.
// Unified 80-slot/step consumption-order stream, u4 = {2 gates x 2 pairs}.
// 3-barrier cross-step pipeline kept verbatim (passed rounds 5-9,11).

typedef _Float16 f16;
typedef _Float16 f16x2 __attribute__((ext_vector_type(2)));
typedef unsigned int u32;

#define T_IN 512
#define T_TOT 1024
#define NBLK 64

__device__ __forceinline__ f16x2 u2h(u32 u) { return __builtin_bit_cast(f16x2, u); }

__device__ __forceinline__ float fdot2f(f16x2 a, f16x2 b, float c) {
#if __has_builtin(__builtin_amdgcn_fdot2)
  return __builtin_amdgcn_fdot2(a, b, c, false);
#else
  return c + (float)a[0] * (float)b[0] + (float)a[1] * (float)b[1];
#endif
}

__device__ __forceinline__ float frcp(float x) {
#if __has_builtin(__builtin_amdgcn_rcpf)
  return __builtin_amdgcn_rcpf(x);
#else
  return 1.f / x;
#endif
}
__device__ __forceinline__ float fsigm(float x) { return frcp(1.f + __expf(-x)); }
__device__ __forceinline__ float ftanh(float x) { return 1.f - 2.f * frcp(1.f + __expf(2.f * x)); }

// ---- weight packing -------------------------------------------------------
// Unified 80-slot/step stream. dst u32[(s*512 + t)*4 + m].
// Thread t: idx=t>>2, g2=(t>>1)&1, kq=t&1. u4 member m: d=m>>1 (pair within
// slot), gate g = 2*g2 + (m&1). Each slot covers 2 column-pairs of a matrix.
//  s<48: q=s/6, rmd=s%6:
//   rmd<4: L2 slot l2=4q+rmd: gp = kq*64+2*l2+d over [Wih2|Whh2] (K=[h1|h2old])
//   rmd>=4: L3e slot l3e=2q+(rmd-4): Whh3 pair kq*32+2*l3e+d    (K=h3_old)
//  s>=48: u=s-48, j=u>>2, r4=u&3:
//   r4<2: L3l slot l=2j+r4: Wih3 pair kq*32+2*l+d               (K=h2_new)
//   r4>=2: L1 slot l=2j+(r4-2): Whh1 pair kq*32+2*l+d           (K=h1 state)
__global__ void pack_stream(u32* dst, const float* Wih2, const float* Whh2,
                            const float* Wih3, const float* Whh3,
                            const float* Whh1) {
  int tid = blockIdx.x * 256 + threadIdx.x;
  if (tid >= 80 * 512 * 4) return;
  int m = tid & 3;
  int t = (tid >> 2) & 511;
  int s = tid >> 11;
  int idx = t >> 2, g2 = (t >> 1) & 1, kq = t & 1;
  int d = m >> 1;
  int g = 2 * g2 + (m & 1);
  const float* src;
  int pairidx;
  if (s < 48) {
    int q = s / 6, rmd = s % 6;
    if (rmd < 4) {
      int l2 = 4 * q + rmd;
      int gp = kq * 64 + 2 * l2 + d;
      if (gp < 64) { src = Wih2; pairidx = gp; }
      else         { src = Whh2; pairidx = gp - 64; }
    } else {
      int l3e = 2 * q + (rmd - 4);
      src = Whh3; pairidx = kq * 32 + 2 * l3e + d;
    }
  } else {
    int u = s - 48, j = u >> 2, r4 = u & 3;
    if (r4 < 2) { int l = 2 * j + r4;       src = Wih3; pairidx = kq * 32 + 2 * l + d; }
    else        { int l = 2 * j + (r4 - 2); src = Whh1; pairidx = kq * 32 + 2 * l + d; }
  }
  int row = g * 128 + idx;
  union { f16 h[2]; u32 u; } cv;
  cv.h[0] = (f16)src[row * 128 + 2 * pairidx];
  cv.h[1] = (f16)src[row * 128 + 2 * pairidx + 1];
  dst[tid] = cv.u;
}

// consT[gg*512 + g*128 + idx]: gg 0=b1,1=b2,2=b3,3=wih1. [2048+idx]=weff, [2176]=beff.
__global__ void prep_cons(float* cons, const float* a1, const float* b1,
                          const float* a2, const float* b2,
                          const float* a3, const float* b3, const float* wih1) {
  int tid = blockIdx.x * 256 + threadIdx.x;
  if (tid >= 2048) return;
  int gg = tid >> 9, g = (tid >> 7) & 3, idx = tid & 127;
  int j = g * 128 + idx;
  float v;
  if (gg == 0) v = a1[j] + b1[j];
  else if (gg == 1) v = a2[j] + b2[j];
  else if (gg == 2) v = a3[j] + b3[j];
  else v = wih1[j];
  cons[tid] = v;
}

__global__ void head_fold(float* cons, const float* lin_w, const float* out_w,
                          const float* Wv, const float* bv,
                          const float* out_b, const float* lin_b) {
  __shared__ float wlo[128];
  __shared__ float pr[128];
  int j = threadIdx.x;
  float s = 0.f;
  for (int k = 0; k < 128; ++k) s += lin_w[k] * out_w[k * 128 + j];
  wlo[j] = s;
  __syncthreads();
  float t = 0.f;
  for (int k = 0; k < 128; ++k) t += wlo[k] * Wv[k * 128 + j];
  cons[2048 + j] = t;
  pr[j] = s * bv[j] + lin_w[j] * out_b[j];
  __syncthreads();
  if (j == 0) {
    float b = lin_b[0];
    for (int k = 0; k < 128; ++k) b += pr[k];
    cons[2176] = b;
  }
}

// consume slot sl: weights ring[sl&7] (issued 8 slots ago), refill (sl+8)%80.
// hp0/hp1 = h pairs for the slot's two column-pairs, per row.
__device__ __forceinline__ void cons(uint4 (&ring)[8], const uint4* __restrict__ Wp,
                                     int sl, const u32 (&hp0)[4], const u32 (&hp1)[4],
                                     float (&A0)[4], float (&A1)[4]) {
  uint4 wv = ring[sl & 7];
  ring[sl & 7] = Wp[((sl + 8) % 80) * 512];
#pragma unroll
  for (int r = 0; r < 4; ++r) {
    A0[r] = fdot2f(u2h(wv.x), u2h(hp0[r]), A0[r]);
    A1[r] = fdot2f(u2h(wv.y), u2h(hp0[r]), A1[r]);
    A0[r] = fdot2f(u2h(wv.z), u2h(hp1[r]), A0[r]);
    A1[r] = fdot2f(u2h(wv.w), u2h(hp1[r]), A1[r]);
  }
}

// gate-split LSTM cell for 4 rows. A0/A1 = own-gate dot sums (pre-reduce).
// e0/e1 = per-row extra pre-activation for own gates (layer1 x-term).
__device__ __forceinline__ void cell(float (&A0)[4], float (&A1)[4],
                                     float bg0, float bg1,
                                     const float (&e0)[4], const float (&e1)[4],
                                     int g2, float (&c)[4], float (&hv)[4]) {
#pragma unroll
  for (int r = 0; r < 4; ++r) {
    float a0 = A0[r]; a0 += __shfl_xor(a0, 1, 64); a0 += bg0 + e0[r];
    float a1 = A1[r]; a1 += __shfl_xor(a1, 1, 64); a1 += bg1 + e1[r];
    float b0 = __shfl_xor(a0, 2, 64);
    float b1 = __shfl_xor(a1, 2, 64);
    float gi = g2 ? b0 : a0;
    float gf = g2 ? b1 : a1;
    float gg = g2 ? a0 : b0;
    float go = g2 ? a1 : b1;
    c[r] = fsigm(gf) * c[r] + fsigm(gi) * ftanh(gg);
    hv[r] = fsigm(go) * ftanh(c[r]);
  }
}

// ---- main persistent kernel ----------------------------------------------
__global__ __launch_bounds__(512) void pendulum_persist(
    const float* __restrict__ input, const uint4* __restrict__ WS,
    const float* __restrict__ consG, float* __restrict__ out) {
  __shared__ __align__(16) f16 h1b[2][4][128];  // [parity][row][idx]
  __shared__ __align__(16) f16 h2b[2][4][128];
  __shared__ __align__(16) f16 h3b[4][128];
  __shared__ float xin[4][T_IN];                // 8 KB
  __shared__ float consL[2180];
  __shared__ float redp[4][8];

  const int t = threadIdx.x;
  const int idx = t >> 2;
  const int g2 = (t >> 1) & 1;
  const int kh = t & 1;  // K-half
  const int row0 = blockIdx.x * 4;

  for (int e = t; e < 2177; e += 512) consL[e] = consG[e];
  for (int e = t; e < 2048; e += 512)
    xin[e >> 9][e & 511] = input[(row0 + (e >> 9)) * T_IN + (e & 511)];
  for (int e = t; e < 1024; e += 512) {
    ((f16*)h1b)[e] = (f16)0.f;
    ((f16*)h2b)[e] = (f16)0.f;
  }
  if (t < 512) ((f16*)h3b)[t] = (f16)0.f;

  const uint4* Wp = WS + t;
  const int g0 = 2 * g2, g1i = 2 * g2 + 1;
  float c1[4] = {0, 0, 0, 0}, c2[4] = {0, 0, 0, 0}, c3[4] = {0, 0, 0, 0};
  __syncthreads();

  const float beffv = consL[2176];
  const float weffr = consL[2048 + idx];
  const float b1g0 = consL[g0 * 128 + idx], b1g1 = consL[g1i * 128 + idx];
  const float b2g0 = consL[512 + g0 * 128 + idx], b2g1 = consL[512 + g1i * 128 + idx];
  const float b3g0 = consL[1024 + g0 * 128 + idx], b3g1 = consL[1024 + g1i * 128 + idx];
  const float wxg0 = consL[1536 + g0 * 128 + idx], wxg1 = consL[1536 + g1i * 128 + idx];
  const float z4[4] = {0, 0, 0, 0};

  // prologue: h1[0] from x[0] only (h1_prev = 0 -> no dots, no kq-reduce)
  {
#pragma unroll
    for (int r = 0; r < 4; ++r) {
      float xr = xin[r][0];
      float a0 = b1g0 + xr * wxg0;
      float a1 = b1g1 + xr * wxg1;
      float b0 = __shfl_xor(a0, 2, 64);
      float b1 = __shfl_xor(a1, 2, 64);
      float gi = g2 ? b0 : a0;
      float gg = g2 ? a0 : b0;
      float go = g2 ? a1 : b1;
      c1[r] = fsigm(gi) * ftanh(gg);
      float h = fsigm(go) * ftanh(c1[r]);
      if ((t & 3) == 0) h1b[0][r][idx] = (f16)h;
    }
    __syncthreads();
  }

  // ring prologue: slots 0..7
  uint4 ring[8];
#pragma unroll
  for (int c = 0; c < 8; ++c) ring[c] = Wp[c * 512];

  for (int s = 0; s < T_TOT; ++s) {
    const int par = s & 1;
    const int xi = (s + 1 < T_IN) ? (s + 1) : 0;

    // h sources (u4 = 4 column-pairs = 2 slots per row)
    const uint4* hL2[4];
    const uint4* h3u[4];
#pragma unroll
    for (int r = 0; r < 4; ++r) {
      hL2[r] = kh ? (const uint4*)&h2b[par ^ 1][r][0] : (const uint4*)&h1b[par][r][0];
      h3u[r] = (const uint4*)&h3b[r][0] + kh * 8;
    }

    float a20[4] = {0, 0, 0, 0}, a21[4] = {0, 0, 0, 0};
    float a30[4] = {0, 0, 0, 0}, a31[4] = {0, 0, 0, 0};

    // ---- P_A: per q: 4 L2 slots + 2 L3-early slots ----
#pragma unroll
    for (int q = 0; q < 8; ++q) {
      uint4 hA[4];
      u32 p0[4], p1[4];
#pragma unroll
      for (int r = 0; r < 4; ++r) hA[r] = hL2[r][2 * q];
#pragma unroll
      for (int r = 0; r < 4; ++r) { p0[r] = hA[r].x; p1[r] = hA[r].y; }
      cons(ring, Wp, 6 * q + 0, p0, p1, a20, a21);
#pragma unroll
      for (int r = 0; r < 4; ++r) { p0[r] = hA[r].z; p1[r] = hA[r].w; }
      cons(ring, Wp, 6 * q + 1, p0, p1, a20, a21);
#pragma unroll
      for (int r = 0; r < 4; ++r) hA[r] = hL2[r][2 * q + 1];
#pragma unroll
      for (int r = 0; r < 4; ++r) { p0[r] = hA[r].x; p1[r] = hA[r].y; }
      cons(ring, Wp, 6 * q + 2, p0, p1, a20, a21);
#pragma unroll
      for (int r = 0; r < 4; ++r) { p0[r] = hA[r].z; p1[r] = hA[r].w; }
      cons(ring, Wp, 6 * q + 3, p0, p1, a20, a21);
#pragma unroll
      for (int r = 0; r < 4; ++r) hA[r] = h3u[r][q];
#pragma unroll
      for (int r = 0; r < 4; ++r) { p0[r] = hA[r].x; p1[r] = hA[r].y; }
      cons(ring, Wp, 6 * q + 4, p0, p1, a30, a31);
#pragma unroll
      for (int r = 0; r < 4; ++r) { p0[r] = hA[r].z; p1[r] = hA[r].w; }
      cons(ring, Wp, 6 * q + 5, p0, p1, a30, a31);
    }

    // layer-2 finish
    {
      float h2v[4];
      cell(a20, a21, b2g0, b2g1, z4, z4, g2, c2, h2v);
      if ((t & 3) == 0) {
#pragma unroll
        for (int r = 0; r < 4; ++r) h2b[par][r][idx] = (f16)h2v[r];
      }
    }
    asm volatile("s_waitcnt lgkmcnt(0)\n\ts_barrier" ::: "memory");  // barrier1

    // ---- P_B: per j: 2 L3-late slots + 2 L1 slots (for step s+1) ----
    const uint4* h2n[4];
    const uint4* h1u[4];
#pragma unroll
    for (int r = 0; r < 4; ++r) {
      h2n[r] = (const uint4*)&h2b[par][r][0] + kh * 8;
      h1u[r] = (const uint4*)&h1b[par][r][0] + kh * 8;
    }
    float a10[4] = {0, 0, 0, 0}, a11[4] = {0, 0, 0, 0};
#pragma unroll
    for (int j = 0; j < 8; ++j) {
      uint4 hA[4];
      u32 p0[4], p1[4];
#pragma unroll
      for (int r = 0; r < 4; ++r) hA[r] = h2n[r][j];
#pragma unroll
      for (int r = 0; r < 4; ++r) { p0[r] = hA[r].x; p1[r] = hA[r].y; }
      cons(ring, Wp, 48 + 4 * j + 0, p0, p1, a30, a31);
#pragma unroll
      for (int r = 0; r < 4; ++r) { p0[r] = hA[r].z; p1[r] = hA[r].w; }
      cons(ring, Wp, 48 + 4 * j + 1, p0, p1, a30, a31);
#pragma unroll
      for (int r = 0; r < 4; ++r) hA[r] = h1u[r][j];
#pragma unroll
      for (int r = 0; r < 4; ++r) { p0[r] = hA[r].x; p1[r] = hA[r].y; }
      cons(ring, Wp, 48 + 4 * j + 2, p0, p1, a10, a11);
#pragma unroll
      for (int r = 0; r < 4; ++r) { p0[r] = hA[r].z; p1[r] = hA[r].w; }
      cons(ring, Wp, 48 + 4 * j + 3, p0, p1, a10, a11);
    }

    // layer-3 finish + head partial
    float h3v[4];
    cell(a30, a31, b3g0, b3g1, z4, z4, g2, c3, h3v);
    if ((t & 3) == 0) {
#pragma unroll
      for (int r = 0; r < 4; ++r) h3b[r][idx] = (f16)h3v[r];
    }
#pragma unroll
    for (int r = 0; r < 4; ++r) {
      float p = ((t & 3) == 0) ? weffr * h3v[r] : 0.f;
#pragma unroll
      for (int k = 1; k < 64; k <<= 1) p += __shfl_xor(p, k, 64);
      if ((t & 63) == 0) redp[r][t >> 6] = p;
    }
    asm volatile("s_waitcnt lgkmcnt(0)\n\ts_barrier" ::: "memory");  // barrier2

    float yv0 = beffv, yv1 = beffv, yv2 = beffv, yv3 = beffv;
#pragma unroll
    for (int w8 = 0; w8 < 8; ++w8) {
      yv0 += redp[0][w8]; yv1 += redp[1][w8];
      yv2 += redp[2][w8]; yv3 += redp[3][w8];
    }
    if (t == 0) out[(row0 + 0) * T_TOT + s] = yv0;
    else if (t == 1) out[(row0 + 1) * T_TOT + s] = yv1;
    else if (t == 2) out[(row0 + 2) * T_TOT + s] = yv2;
    else if (t == 3) out[(row0 + 3) * T_TOT + s] = yv3;

    // layer-1 finish for step s+1
    {
      float xv[4];
      xv[0] = (s + 1 < T_IN) ? xin[0][xi] : yv0;
      xv[1] = (s + 1 < T_IN) ? xin[1][xi] : yv1;
      xv[2] = (s + 1 < T_IN) ? xin[2][xi] : yv2;
      xv[3] = (s + 1 < T_IN) ? xin[3][xi] : yv3;
      float e0[4], e1[4];
#pragma unroll
      for (int r = 0; r < 4; ++r) { e0[r] = xv[r] * wxg0; e1[r] = xv[r] * wxg1; }
      float h1v[4];
      cell(a10, a11, b1g0, b1g1, e0, e1, g2, c1, h1v);
      if ((t & 3) == 0) {
#pragma unroll
        for (int r = 0; r < 4; ++r) h1b[par ^ 1][r][idx] = (f16)h1v[r];
      }
    }
    asm volatile("s_waitcnt lgkmcnt(0)\n\ts_barrier" ::: "memory");  // barrier3
  }
}

// ---- launch ---------------------------------------------------------------
extern "C" void kernel_launch(void* const* d_in, const int* in_sizes, int n_in,
                              void* d_out, int out_size, void* d_ws, size_t ws_size,
                              hipStream_t stream) {
  const float* input = (const float*)d_in[0];
  const float* Wih1 = (const float*)d_in[2];
  const float* Whh1 = (const float*)d_in[3];
  const float* bih1 = (const float*)d_in[4];
  const float* bhh1 = (const float*)d_in[5];
  const float* Wih2 = (const float*)d_in[6];
  const float* Whh2 = (const float*)d_in[7];
  const float* bih2 = (const float*)d_in[8];
  const float* bhh2 = (const float*)d_in[9];
  const float* Wih3 = (const float*)d_in[10];
  const float* Whh3 = (const float*)d_in[11];
  const float* bih3 = (const float*)d_in[12];
  const float* bhh3 = (const float*)d_in[13];
  const float* in_proj_w = (const float*)d_in[14];
  const float* in_proj_b = (const float*)d_in[15];
  const float* out_w = (const float*)d_in[16];
  const float* out_b = (const float*)d_in[17];
  const float* lin_w = (const float*)d_in[18];
  const float* lin_b = (const float*)d_in[19];

  char* ws = (char*)d_ws;
  u32* WS = (u32*)(ws + (0 << 10));          // 640 KB unified stream
  float* consG = (float*)(ws + (640 << 10)); // ~8.7 KB

  pack_stream<<<640, 256, 0, stream>>>(WS, Wih2, Whh2, Wih3, Whh3, Whh1);
  prep_cons<<<8, 256, 0, stream>>>(consG, bih1, bhh1, bih2, bhh2, bih3, bhh3, Wih1);
  head_fold<<<1, 128, 0, stream>>>(consG, lin_w, out_w,
                                   in_proj_w + 2 * 128 * 128, in_proj_b + 256,
                                   out_b, lin_b);

  pendulum_persist<<<NBLK, 512, 0, stream>>>(
      input, (const uint4*)WS, consG, (float*)d_out);
}

// Round 14
// 26565.244 us; speedup vs baseline: 1.1417x; 1.1417x over previous
//
#include <hip/hip_runtime.h>

// Pendulum 3-layer LSTM (H=128), B=256 rows, 1024 sequential steps.
// Head collapsed to y = weff.h3 + beff (exact fp32 precompute).
//
// ROUND 14 = ROUND 13 with two fixes:
//  1) RING BUG: 20-slot stream with 8-deep ring broke the position invariant
//     (20 % 8 != 0) -> wrong weights after wrap (absmax 2.2e-3). Ring is now
//     depth 10 (divides 20), indices compile-time folded.
//  2) Group mapping g = bid&63, sub = bid>>6: cooperating blocks share an XCD
//     under round-robin dispatch -> flag/h exchange through one L2.
// Design: 256 blocks x 512 thr; group g handles rows 4g..4g+3; sub owns
// idx quarter [32*sub, 32*sub+32) of ALL layers -> 160KB/step/block stream
// (breaks the ~25 B/cy/CU ingest ceiling measured in rounds 9/11).
// h quarters + head partials exchanged via global hx[] with agent-scope
// release/acquire flags; 3 group syncs/step; all 256 blocks co-resident.

typedef _Float16 f16;
typedef _Float16 f16x2 __attribute__((ext_vector_type(2)));
typedef unsigned int u32;

#define T_IN 512
#define T_TOT 1024

__device__ __forceinline__ f16x2 u2h(u32 u) { return __builtin_bit_cast(f16x2, u); }

__device__ __forceinline__ float fdot2f(f16x2 a, f16x2 b, float c) {
#if __has_builtin(__builtin_amdgcn_fdot2)
  return __builtin_amdgcn_fdot2(a, b, c, false);
#else
  return c + (float)a[0] * (float)b[0] + (float)a[1] * (float)b[1];
#endif
}

__device__ __forceinline__ float frcp(float x) {
#if __has_builtin(__builtin_amdgcn_rcpf)
  return __builtin_amdgcn_rcpf(x);
#else
  return 1.f / x;
#endif
}
__device__ __forceinline__ float fsigm(float x) { return frcp(1.f + __expf(-x)); }
__device__ __forceinline__ float ftanh(float x) { return 1.f - 2.f * frcp(1.f + __expf(2.f * x)); }

// ---- weight packing -------------------------------------------------------
// WS[((sub*20 + slot)*512 + t)*4 + m], thread t: i=t>>4 (idx-local), kq=t&15.
// idx = sub*32+i, gate row j = m*128+idx.
//  slot<4:   L1: pair cp = kq*4+slot of Whh1            (operand h1_old)
//  4..11:    L2: p = kq*8+(slot-4); p<64: Wih2 cp=p (h1_new) else Whh2 cp=p-64 (h2_old)
//  12..19:   L3: p = kq*8+(slot-12); p<64: Wih3 cp=p (h2_new) else Whh3 cp=p-64 (h3_old)
__global__ void pack_ws(u32* dst, const float* Whh1, const float* Wih2,
                        const float* Whh2, const float* Wih3, const float* Whh3) {
  int tid = blockIdx.x * 256 + threadIdx.x;
  if (tid >= 4 * 20 * 512 * 4) return;
  int m = tid & 3;
  int t = (tid >> 2) & 511;
  int sg = tid >> 11;  // sub*20 + slot
  int slot = sg % 20, sub = sg / 20;
  int i = t >> 4, kq = t & 15;
  int idx = sub * 32 + i;
  int j = m * 128 + idx;
  const float* src;
  int cp;
  if (slot < 4) { src = Whh1; cp = kq * 4 + slot; }
  else if (slot < 12) {
    int p = kq * 8 + (slot - 4);
    if (p < 64) { src = Wih2; cp = p; } else { src = Whh2; cp = p - 64; }
  } else {
    int p = kq * 8 + (slot - 12);
    if (p < 64) { src = Wih3; cp = p; } else { src = Whh3; cp = p - 64; }
  }
  union { f16 h[2]; u32 u; } cv;
  cv.h[0] = (f16)src[j * 128 + 2 * cp];
  cv.h[1] = (f16)src[j * 128 + 2 * cp + 1];
  dst[tid] = cv.u;
}

// consT[gg*512 + g*128 + idx]: gg 0=b1,1=b2,2=b3,3=wih1. [2048+idx]=weff, [2176]=beff.
__global__ void prep_cons(float* cons, const float* a1, const float* b1,
                          const float* a2, const float* b2,
                          const float* a3, const float* b3, const float* wih1) {
  int tid = blockIdx.x * 256 + threadIdx.x;
  if (tid >= 2048) return;
  int gg = tid >> 9, g = (tid >> 7) & 3, idx = tid & 127;
  int j = g * 128 + idx;
  float v;
  if (gg == 0) v = a1[j] + b1[j];
  else if (gg == 1) v = a2[j] + b2[j];
  else if (gg == 2) v = a3[j] + b3[j];
  else v = wih1[j];
  cons[tid] = v;
}

__global__ void head_fold(float* cons, const float* lin_w, const float* out_w,
                          const float* Wv, const float* bv,
                          const float* out_b, const float* lin_b) {
  __shared__ float wlo[128];
  __shared__ float pr[128];
  int j = threadIdx.x;
  float s = 0.f;
  for (int k = 0; k < 128; ++k) s += lin_w[k] * out_w[k * 128 + j];
  wlo[j] = s;
  __syncthreads();
  float t = 0.f;
  for (int k = 0; k < 128; ++k) t += wlo[k] * Wv[k * 128 + j];
  cons[2048 + j] = t;
  pr[j] = s * bv[j] + lin_w[j] * out_b[j];
  __syncthreads();
  if (j == 0) {
    float b = lin_b[0];
    for (int k = 0; k < 128; ++k) b += pr[k];
    cons[2176] = b;
  }
}

__global__ void zero_ws(u32* p, int n) {
  int tid = blockIdx.x * 256 + threadIdx.x;
  if (tid < n) p[tid] = 0;
}

// consume slot sl (compile-time): dots vs 4 rows, refill slot (sl+10)%20
// into ring[sl%10] (position invariant holds because 10 | 20).
__device__ __forceinline__ void cons20(uint4 (&ring)[10], const uint4* __restrict__ Wp,
                                       int sl, const u32 (&hv)[4], float (&a)[4][4]) {
  uint4 wv = ring[sl % 10];
  ring[sl % 10] = Wp[((sl + 10) % 20) * 512];
#pragma unroll
  for (int r = 0; r < 4; ++r) {
    f16x2 hh = u2h(hv[r]);
    a[0][r] = fdot2f(u2h(wv.x), hh, a[0][r]);
    a[1][r] = fdot2f(u2h(wv.y), hh, a[1][r]);
    a[2][r] = fdot2f(u2h(wv.z), hh, a[2][r]);
    a[3][r] = fdot2f(u2h(wv.w), hh, a[3][r]);
  }
}

// ---- main persistent kernel ----------------------------------------------
__global__ __launch_bounds__(512) void pendulum_persist(
    const float* __restrict__ input, const uint4* __restrict__ WS,
    const float* __restrict__ consG, f16* __restrict__ hx,
    float* __restrict__ partials, u32* __restrict__ flags,
    float* __restrict__ out) {
  __shared__ __align__(16) f16 hL[3][2][4][128];  // [layer][parity][row][idx]
  __shared__ float xin[4][T_IN];
  __shared__ float consL[2180];
  __shared__ float prL[32][4];
  __shared__ float ybuf[4];

  const int t = threadIdx.x;
  const int i = t >> 4, kq = t & 15;
  const int g = blockIdx.x & 63, sub = blockIdx.x >> 6;  // same-XCD group
  const int idx = sub * 32 + i;

  for (int e = t; e < 2177; e += 512) consL[e] = consG[e];
  for (int e = t; e < 2048; e += 512)
    xin[e >> 9][e & 511] = input[(g * 4 + (e >> 9)) * T_IN + (e & 511)];
  for (int e = t; e < 3 * 2 * 4 * 128; e += 512) ((f16*)hL)[e] = (f16)0.f;
  __syncthreads();

  const uint4* Wp = WS + sub * 20 * 512 + t;
  u32* myflag = flags + (g * 4 + sub);

  float c1[4] = {0, 0, 0, 0}, c2[4] = {0, 0, 0, 0}, c3[4] = {0, 0, 0, 0};
  const float weffr = consL[2048 + idx];
  const float beffv = consL[2176];

  uint4 ring[10];
#pragma unroll
  for (int c = 0; c < 10; ++c) ring[c] = Wp[c * 512];

#define KREDUCE(a)                                             \
  _Pragma("unroll") for (int m = 0; m < 4; ++m)                \
  _Pragma("unroll") for (int r = 0; r < 4; ++r) {              \
    float v = a[m][r];                                         \
    v += __shfl_xor(v, 1, 64); v += __shfl_xor(v, 2, 64);      \
    v += __shfl_xor(v, 4, 64); v += __shfl_xor(v, 8, 64);      \
    a[m][r] = v;                                               \
  }

#define FLAG_SPIN(ph)                                                          \
  do {                                                                         \
    u32 tgt = 3u * (u32)s + (ph) + 1u;                                         \
    if (t == 0)                                                                \
      __hip_atomic_store(myflag, tgt, __ATOMIC_RELEASE,                        \
                         __HIP_MEMORY_SCOPE_AGENT);                            \
    if (t >= 1 && t <= 3) {                                                    \
      u32* pf = flags + g * 4 + ((sub + t) & 3);                               \
      while (__hip_atomic_load(pf, __ATOMIC_ACQUIRE,                           \
                               __HIP_MEMORY_SCOPE_AGENT) < tgt) {}             \
    }                                                                          \
  } while (0)

#define COPY_PARTNERS(L, ps)                                                   \
  if (t < 48) {                                                                \
    int r = t / 12, k = t % 12;                                                \
    int qs = (sub + 1 + (k >> 2)) & 3;                                         \
    int ch = k & 3;                                                            \
    uint4 v = *(const uint4*)(hx + ((((ps) * 3 + (L)) * 64 + g) * 4 + r) * 128 \
                              + qs * 32 + ch * 8);                             \
    *(uint4*)&hL[L][ps][r][qs * 32 + ch * 8] = v;                              \
  }

  for (int s = 0; s < T_TOT; ++s) {
    const int par = s & 1, ps = par ^ 1;
    float a[4][4];

    // ================= P1: layer 1 (slots 0..3, K = h1_old) =================
#pragma unroll
    for (int m = 0; m < 4; ++m)
#pragma unroll
      for (int r = 0; r < 4; ++r) a[m][r] = 0.f;
    {
      uint4 hv4[4];
#pragma unroll
      for (int r = 0; r < 4; ++r)
        hv4[r] = *(const uint4*)((const char*)&hL[0][par][r][0] + kq * 16);
#pragma unroll
      for (int sl = 0; sl < 4; ++sl) {
        u32 hv[4];
#pragma unroll
        for (int r = 0; r < 4; ++r) hv[r] = ((const u32*)&hv4[r])[sl];
        cons20(ring, Wp, sl, hv, a);
      }
    }
    KREDUCE(a);
    if (kq == 0) {
#pragma unroll
      for (int r = 0; r < 4; ++r) {
        float xs = (s < T_IN) ? xin[r][s] : ybuf[r];
        float gi = fsigm(a[0][r] + consL[idx] + xs * consL[1536 + idx]);
        float gf = fsigm(a[1][r] + consL[128 + idx] + xs * consL[1664 + idx]);
        float gg = ftanh(a[2][r] + consL[256 + idx] + xs * consL[1792 + idx]);
        float go = fsigm(a[3][r] + consL[384 + idx] + xs * consL[1920 + idx]);
        c1[r] = gf * c1[r] + gi * gg;
        float h = go * ftanh(c1[r]);
        hL[0][ps][r][idx] = (f16)h;
        hx[((ps * 3 + 0) * 64 + g) * 512 + r * 128 + idx] = (f16)h;
      }
    }
    asm volatile("s_waitcnt vmcnt(0)" ::: "memory");
    __builtin_amdgcn_s_barrier();
    FLAG_SPIN(0);
    __builtin_amdgcn_s_barrier();
    COPY_PARTNERS(0, ps);
    asm volatile("s_waitcnt lgkmcnt(0)" ::: "memory");
    __builtin_amdgcn_s_barrier();

    // ============ P2: layer 2 (slots 4..11, K = [h1_new | h2_old]) ==========
#pragma unroll
    for (int m = 0; m < 4; ++m)
#pragma unroll
      for (int r = 0; r < 4; ++r) a[m][r] = 0.f;
#pragma unroll
    for (int half = 0; half < 2; ++half) {
      uint4 hv4[4];
#pragma unroll
      for (int r = 0; r < 4; ++r) {
        const char* base = (kq < 8) ? (const char*)&hL[0][ps][r][0]
                                    : (const char*)&hL[1][par][r][0];
        hv4[r] = *(const uint4*)(base + (kq & 7) * 32 + half * 16);
      }
#pragma unroll
      for (int e = 0; e < 4; ++e) {
        u32 hv[4];
#pragma unroll
        for (int r = 0; r < 4; ++r) hv[r] = ((const u32*)&hv4[r])[e];
        cons20(ring, Wp, 4 + half * 4 + e, hv, a);
      }
    }
    KREDUCE(a);
    if (kq == 0) {
#pragma unroll
      for (int r = 0; r < 4; ++r) {
        float gi = fsigm(a[0][r] + consL[512 + idx]);
        float gf = fsigm(a[1][r] + consL[640 + idx]);
        float gg = ftanh(a[2][r] + consL[768 + idx]);
        float go = fsigm(a[3][r] + consL[896 + idx]);
        c2[r] = gf * c2[r] + gi * gg;
        float h = go * ftanh(c2[r]);
        hL[1][ps][r][idx] = (f16)h;
        hx[((ps * 3 + 1) * 64 + g) * 512 + r * 128 + idx] = (f16)h;
      }
    }
    asm volatile("s_waitcnt vmcnt(0)" ::: "memory");
    __builtin_amdgcn_s_barrier();
    FLAG_SPIN(1);
    __builtin_amdgcn_s_barrier();
    COPY_PARTNERS(1, ps);
    asm volatile("s_waitcnt lgkmcnt(0)" ::: "memory");
    __builtin_amdgcn_s_barrier();

    // ============ P3: layer 3 (slots 12..19, K = [h2_new | h3_old]) =========
#pragma unroll
    for (int m = 0; m < 4; ++m)
#pragma unroll
      for (int r = 0; r < 4; ++r) a[m][r] = 0.f;
#pragma unroll
    for (int half = 0; half < 2; ++half) {
      uint4 hv4[4];
#pragma unroll
      for (int r = 0; r < 4; ++r) {
        const char* base = (kq < 8) ? (const char*)&hL[1][ps][r][0]
                                    : (const char*)&hL[2][par][r][0];
        hv4[r] = *(const uint4*)(base + (kq & 7) * 32 + half * 16);
      }
#pragma unroll
      for (int e = 0; e < 4; ++e) {
        u32 hv[4];
#pragma unroll
        for (int r = 0; r < 4; ++r) hv[r] = ((const u32*)&hv4[r])[e];
        cons20(ring, Wp, 12 + half * 4 + e, hv, a);
      }
    }
    KREDUCE(a);
    if (kq == 0) {
#pragma unroll
      for (int r = 0; r < 4; ++r) {
        float gi = fsigm(a[0][r] + consL[1024 + idx]);
        float gf = fsigm(a[1][r] + consL[1152 + idx]);
        float gg = ftanh(a[2][r] + consL[1280 + idx]);
        float go = fsigm(a[3][r] + consL[1408 + idx]);
        c3[r] = gf * c3[r] + gi * gg;
        float h = go * ftanh(c3[r]);
        hL[2][ps][r][idx] = (f16)h;
        hx[((ps * 3 + 2) * 64 + g) * 512 + r * 128 + idx] = (f16)h;
        prL[i][r] = weffr * h;
      }
    }
    asm volatile("s_waitcnt lgkmcnt(0)" ::: "memory");
    __builtin_amdgcn_s_barrier();
    if (t < 4) {
      float sum = 0.f;
#pragma unroll 8
      for (int ii = 0; ii < 32; ++ii) sum += prL[ii][t];
      partials[(g * 4 + sub) * 4 + t] = sum;
    }
    asm volatile("s_waitcnt vmcnt(0)" ::: "memory");
    __builtin_amdgcn_s_barrier();
    FLAG_SPIN(2);
    __builtin_amdgcn_s_barrier();
    COPY_PARTNERS(2, ps);
    if (t < 4) {
      float y = beffv;
#pragma unroll
      for (int ss = 0; ss < 4; ++ss) y += partials[(g * 4 + ss) * 4 + t];
      ybuf[t] = y;
      if (sub == 0) out[(g * 4 + t) * T_TOT + s] = y;
    }
    asm volatile("s_waitcnt lgkmcnt(0)" ::: "memory");
    __builtin_amdgcn_s_barrier();
  }
#undef KREDUCE
#undef FLAG_SPIN
#undef COPY_PARTNERS
}

// ---- launch ---------------------------------------------------------------
extern "C" void kernel_launch(void* const* d_in, const int* in_sizes, int n_in,
                              void* d_out, int out_size, void* d_ws, size_t ws_size,
                              hipStream_t stream) {
  const float* input = (const float*)d_in[0];
  const float* Wih1 = (const float*)d_in[2];
  const float* Whh1 = (const float*)d_in[3];
  const float* bih1 = (const float*)d_in[4];
  const float* bhh1 = (const float*)d_in[5];
  const float* Wih2 = (const float*)d_in[6];
  const float* Whh2 = (const float*)d_in[7];
  const float* bih2 = (const float*)d_in[8];
  const float* bhh2 = (const float*)d_in[9];
  const float* Wih3 = (const float*)d_in[10];
  const float* Whh3 = (const float*)d_in[11];
  const float* bih3 = (const float*)d_in[12];
  const float* bhh3 = (const float*)d_in[13];
  const float* in_proj_w = (const float*)d_in[14];
  const float* in_proj_b = (const float*)d_in[15];
  const float* out_w = (const float*)d_in[16];
  const float* out_b = (const float*)d_in[17];
  const float* lin_w = (const float*)d_in[18];
  const float* lin_b = (const float*)d_in[19];

  char* ws = (char*)d_ws;
  u32* WS = (u32*)(ws + 0);                    // 640 KB split streams
  float* consG = (float*)(ws + (640 << 10));   // ~8.7 KB
  f16* hx = (f16*)(ws + (672 << 10));          // 384 KB h exchange
  float* partials = (float*)(ws + (1056 << 10));  // 4 KB
  u32* flags = (u32*)(ws + (1060 << 10));      // 1 KB

  pack_ws<<<640, 256, 0, stream>>>(WS, Whh1, Wih2, Whh2, Wih3, Whh3);
  prep_cons<<<8, 256, 0, stream>>>(consG, bih1, bhh1, bih2, bhh2, bih3, bhh3, Wih1);
  head_fold<<<1, 128, 0, stream>>>(consG, lin_w, out_w,
                                   in_proj_w + 2 * 128 * 128, in_proj_b + 256,
                                   out_b, lin_b);
  // zero hx + partials + flags
  zero_ws<<<((1061 - 672) << 10) / 4 / 256 + 1, 256, 0, stream>>>(
      (u32*)(ws + (672 << 10)), ((1061 - 672) << 10) / 4);

  pendulum_persist<<<256, 512, 0, stream>>>(
      input, (const uint4*)WS, consG, hx, partials, flags, (float*)d_out);
}

// Round 15
// 15981.485 us; speedup vs baseline: 1.8978x; 1.6623x over previous
//
#include <hip/hip_runtime.h>

// Pendulum 3-layer LSTM (H=128), B=256 rows, 1024 sequential steps.
// Head collapsed to y = weff.h3 + beff (exact fp32 precompute).
//
// ROUND 15: discriminating experiment — is round 9's 8.86us/step a per-CU
// ingest ceiling (~24 B/cy) or a prefetch-distance stall (8-deep ring lead
// ~350cy < ~500cy L2 latency)?
//   64 blocks x 512 threads x 4 ROWS/block (no cross-block anything).
//   Thread = (idx 128, kq 4), round-9 map. Layer-sequential phases
//   (L1:16 / L2:32 / L3:32 slots) cap live acc at 16 (round-12's gate-split
//   redundancy mistake avoided). Unified 80-slot consumption-order stream,
//   register ring depth 10 (80%10==0, position invariant holds).
//   Per slot: 16 fdot2 (~32cy issue) -> lead = 9 slots x 32 x 2-wave
//   interleave ~576cy wall >= L2 latency -> stalls gone IF stall model true.
//   3 in-block barriers/step; h buffers parity-double-buffered.

typedef _Float16 f16;
typedef _Float16 f16x2 __attribute__((ext_vector_type(2)));
typedef unsigned int u32;

#define T_IN 512
#define T_TOT 1024
#define NBLK 64

__device__ __forceinline__ f16x2 u2h(u32 u) { return __builtin_bit_cast(f16x2, u); }

__device__ __forceinline__ float fdot2f(f16x2 a, f16x2 b, float c) {
#if __has_builtin(__builtin_amdgcn_fdot2)
  return __builtin_amdgcn_fdot2(a, b, c, false);
#else
  return c + (float)a[0] * (float)b[0] + (float)a[1] * (float)b[1];
#endif
}

__device__ __forceinline__ float frcp(float x) {
#if __has_builtin(__builtin_amdgcn_rcpf)
  return __builtin_amdgcn_rcpf(x);
#else
  return 1.f / x;
#endif
}
__device__ __forceinline__ float fsigm(float x) { return frcp(1.f + __expf(-x)); }
__device__ __forceinline__ float ftanh(float x) { return 1.f - 2.f * frcp(1.f + __expf(2.f * x)); }

// ---- weight packing -------------------------------------------------------
// WS[(slot*512 + t)*4 + g], thread t: idx=t>>2, kq=t&3. 80 slots/step:
//  slot<16:  L1: Whh1 pair cp = kq*16 + slot              (K = h1_old)
//  16..47:   L2: p = kq*32 + (slot-16); p<64: Wih2 cp=p (h1_new)
//            else Whh2 cp=p-64 (h2_old)
//  48..79:   L3: p = kq*32 + (slot-48); p<64: Wih3 cp=p (h2_new)
//            else Whh3 cp=p-64 (h3_old)
// u4 member g: half2{ W[g*128+idx][2cp], W[g*128+idx][2cp+1] }, gates i,f,g,o.
__global__ void pack_ws(u32* dst, const float* Whh1, const float* Wih2,
                        const float* Whh2, const float* Wih3, const float* Whh3) {
  int tid = blockIdx.x * 256 + threadIdx.x;
  if (tid >= 80 * 512 * 4) return;
  int g = tid & 3;
  int t = (tid >> 2) & 511;
  int slot = tid >> 11;
  int idx = t >> 2, kq = t & 3;
  const float* src;
  int cp;
  if (slot < 16) {
    src = Whh1; cp = kq * 16 + slot;
  } else if (slot < 48) {
    int p = kq * 32 + (slot - 16);
    if (p < 64) { src = Wih2; cp = p; } else { src = Whh2; cp = p - 64; }
  } else {
    int p = kq * 32 + (slot - 48);
    if (p < 64) { src = Wih3; cp = p; } else { src = Whh3; cp = p - 64; }
  }
  int j = g * 128 + idx;
  union { f16 h[2]; u32 u; } cv;
  cv.h[0] = (f16)src[j * 128 + 2 * cp];
  cv.h[1] = (f16)src[j * 128 + 2 * cp + 1];
  dst[tid] = cv.u;
}

// consT[gg*512 + g*128 + idx]: gg 0=b1,1=b2,2=b3,3=wih1. [2048+idx]=weff, [2176]=beff.
__global__ void prep_cons(float* cons, const float* a1, const float* b1,
                          const float* a2, const float* b2,
                          const float* a3, const float* b3, const float* wih1) {
  int tid = blockIdx.x * 256 + threadIdx.x;
  if (tid >= 2048) return;
  int gg = tid >> 9, g = (tid >> 7) & 3, idx = tid & 127;
  int j = g * 128 + idx;
  float v;
  if (gg == 0) v = a1[j] + b1[j];
  else if (gg == 1) v = a2[j] + b2[j];
  else if (gg == 2) v = a3[j] + b3[j];
  else v = wih1[j];
  cons[tid] = v;
}

__global__ void head_fold(float* cons, const float* lin_w, const float* out_w,
                          const float* Wv, const float* bv,
                          const float* out_b, const float* lin_b) {
  __shared__ float wlo[128];
  __shared__ float pr[128];
  int j = threadIdx.x;
  float s = 0.f;
  for (int k = 0; k < 128; ++k) s += lin_w[k] * out_w[k * 128 + j];
  wlo[j] = s;
  __syncthreads();
  float t = 0.f;
  for (int k = 0; k < 128; ++k) t += wlo[k] * Wv[k * 128 + j];
  cons[2048 + j] = t;
  pr[j] = s * bv[j] + lin_w[j] * out_b[j];
  __syncthreads();
  if (j == 0) {
    float b = lin_b[0];
    for (int k = 0; k < 128; ++k) b += pr[k];
    cons[2176] = b;
  }
}

// consume slot sl (compile-time): 16 fdot2 (4 gates x 4 rows), refill
// slot (sl+10)%80 into ring[sl%10] (invariant holds: 10 | 80).
__device__ __forceinline__ void cons80(uint4 (&ring)[10], const uint4* __restrict__ Wp,
                                       int sl, const u32 (&hv)[4], float (&a)[4][4]) {
  uint4 wv = ring[sl % 10];
  ring[sl % 10] = Wp[((sl + 10) % 80) * 512];
#pragma unroll
  for (int r = 0; r < 4; ++r) {
    f16x2 hh = u2h(hv[r]);
    a[0][r] = fdot2f(u2h(wv.x), hh, a[0][r]);
    a[1][r] = fdot2f(u2h(wv.y), hh, a[1][r]);
    a[2][r] = fdot2f(u2h(wv.z), hh, a[2][r]);
    a[3][r] = fdot2f(u2h(wv.w), hh, a[3][r]);
  }
}

// ---- main persistent kernel ----------------------------------------------
__global__ __launch_bounds__(512) void pendulum_persist(
    const float* __restrict__ input, const uint4* __restrict__ WS,
    const float* __restrict__ consG, float* __restrict__ out) {
  __shared__ __align__(16) f16 h1b[2][4][128];  // [parity][row][idx]
  __shared__ __align__(16) f16 h2b[2][4][128];
  __shared__ __align__(16) f16 h3b[2][4][128];
  __shared__ float xin[4][T_IN];                // 8 KB
  __shared__ float consL[2180];
  __shared__ float redp[4][8];

  const int t = threadIdx.x;
  const int idx = t >> 2;
  const int kq = t & 3;
  const int row0 = blockIdx.x * 4;

  for (int e = t; e < 2177; e += 512) consL[e] = consG[e];
  for (int e = t; e < 2048; e += 512)
    xin[e >> 9][e & 511] = input[(row0 + (e >> 9)) * T_IN + (e & 511)];
  for (int e = t; e < 1024; e += 512) {
    ((f16*)h1b)[e] = (f16)0.f;
    ((f16*)h2b)[e] = (f16)0.f;
    ((f16*)h3b)[e] = (f16)0.f;
  }
  __syncthreads();

  const uint4* Wp = WS + t;
  float c1[4] = {0, 0, 0, 0}, c2[4] = {0, 0, 0, 0}, c3[4] = {0, 0, 0, 0};
  float yv0 = 0.f, yv1 = 0.f, yv2 = 0.f, yv3 = 0.f;

  const float beffv = consL[2176];
  const float weffr = consL[2048 + idx];

  uint4 ring[10];
#pragma unroll
  for (int c = 0; c < 10; ++c) ring[c] = Wp[c * 512];

#define KRED4(a)                                               \
  _Pragma("unroll") for (int m = 0; m < 4; ++m)                \
  _Pragma("unroll") for (int r = 0; r < 4; ++r) {              \
    float v = a[m][r];                                         \
    v += __shfl_xor(v, 1, 64);                                 \
    v += __shfl_xor(v, 2, 64);                                 \
    a[m][r] = v;                                               \
  }

  for (int s = 0; s < T_TOT; ++s) {
    const int par = s & 1, ps = par ^ 1;
    float a[4][4];

    // ================= P1: layer 1 (slots 0..15, K = h1_old) ================
#pragma unroll
    for (int m = 0; m < 4; ++m)
#pragma unroll
      for (int r = 0; r < 4; ++r) a[m][r] = 0.f;
#pragma unroll
    for (int q4 = 0; q4 < 4; ++q4) {
      uint4 hv4[4];
#pragma unroll
      for (int r = 0; r < 4; ++r)
        hv4[r] = *((const uint4*)&h1b[par][r][kq * 32] + q4);
#pragma unroll
      for (int e = 0; e < 4; ++e) {
        u32 hv[4];
#pragma unroll
        for (int r = 0; r < 4; ++r) hv[r] = ((const u32*)&hv4[r])[e];
        cons80(ring, Wp, q4 * 4 + e, hv, a);
      }
    }
    KRED4(a);
    if (kq == 0) {
#pragma unroll
      for (int r = 0; r < 4; ++r) {
        float xs;
        if (r == 0) xs = (s < T_IN) ? xin[0][s] : yv0;
        else if (r == 1) xs = (s < T_IN) ? xin[1][s] : yv1;
        else if (r == 2) xs = (s < T_IN) ? xin[2][s] : yv2;
        else xs = (s < T_IN) ? xin[3][s] : yv3;
        float gi = fsigm(a[0][r] + consL[idx] + xs * consL[1536 + idx]);
        float gf = fsigm(a[1][r] + consL[128 + idx] + xs * consL[1664 + idx]);
        float gg = ftanh(a[2][r] + consL[256 + idx] + xs * consL[1792 + idx]);
        float go = fsigm(a[3][r] + consL[384 + idx] + xs * consL[1920 + idx]);
        c1[r] = gf * c1[r] + gi * gg;
        h1b[ps][r][idx] = (f16)(go * ftanh(c1[r]));
      }
    }
    asm volatile("s_waitcnt lgkmcnt(0)\n\ts_barrier" ::: "memory");  // barrier1

    // ============ P2: layer 2 (slots 16..47, K = [h1_new | h2_old]) =========
#pragma unroll
    for (int m = 0; m < 4; ++m)
#pragma unroll
      for (int r = 0; r < 4; ++r) a[m][r] = 0.f;
#pragma unroll
    for (int q8 = 0; q8 < 8; ++q8) {
      uint4 hv4[4];
#pragma unroll
      for (int r = 0; r < 4; ++r) {
        const f16* base = (kq < 2) ? &h1b[ps][r][kq * 64] : &h2b[par][r][(kq - 2) * 64];
        hv4[r] = *((const uint4*)base + q8);
      }
#pragma unroll
      for (int e = 0; e < 4; ++e) {
        u32 hv[4];
#pragma unroll
        for (int r = 0; r < 4; ++r) hv[r] = ((const u32*)&hv4[r])[e];
        cons80(ring, Wp, 16 + q8 * 4 + e, hv, a);
      }
    }
    KRED4(a);
    if (kq == 0) {
#pragma unroll
      for (int r = 0; r < 4; ++r) {
        float gi = fsigm(a[0][r] + consL[512 + idx]);
        float gf = fsigm(a[1][r] + consL[640 + idx]);
        float gg = ftanh(a[2][r] + consL[768 + idx]);
        float go = fsigm(a[3][r] + consL[896 + idx]);
        c2[r] = gf * c2[r] + gi * gg;
        h2b[ps][r][idx] = (f16)(go * ftanh(c2[r]));
      }
    }
    asm volatile("s_waitcnt lgkmcnt(0)\n\ts_barrier" ::: "memory");  // barrier2

    // ============ P3: layer 3 (slots 48..79, K = [h2_new | h3_old]) =========
#pragma unroll
    for (int m = 0; m < 4; ++m)
#pragma unroll
      for (int r = 0; r < 4; ++r) a[m][r] = 0.f;
#pragma unroll
    for (int q8 = 0; q8 < 8; ++q8) {
      uint4 hv4[4];
#pragma unroll
      for (int r = 0; r < 4; ++r) {
        const f16* base = (kq < 2) ? &h2b[ps][r][kq * 64] : &h3b[par][r][(kq - 2) * 64];
        hv4[r] = *((const uint4*)base + q8);
      }
#pragma unroll
      for (int e = 0; e < 4; ++e) {
        u32 hv[4];
#pragma unroll
        for (int r = 0; r < 4; ++r) hv[r] = ((const u32*)&hv4[r])[e];
        cons80(ring, Wp, 48 + q8 * 4 + e, hv, a);
      }
    }
    KRED4(a);
    float h3v[4];
    if (kq == 0) {
#pragma unroll
      for (int r = 0; r < 4; ++r) {
        float gi = fsigm(a[0][r] + consL[1024 + idx]);
        float gf = fsigm(a[1][r] + consL[1152 + idx]);
        float gg = ftanh(a[2][r] + consL[1280 + idx]);
        float go = fsigm(a[3][r] + consL[1408 + idx]);
        c3[r] = gf * c3[r] + gi * gg;
        h3v[r] = go * ftanh(c3[r]);
        h3b[ps][r][idx] = (f16)h3v[r];
      }
    }
#pragma unroll
    for (int r = 0; r < 4; ++r) {
      float p = (kq == 0) ? weffr * h3v[r] : 0.f;
#pragma unroll
      for (int k = 1; k < 64; k <<= 1) p += __shfl_xor(p, k, 64);
      if ((t & 63) == 0) redp[r][t >> 6] = p;
    }
    asm volatile("s_waitcnt lgkmcnt(0)\n\ts_barrier" ::: "memory");  // barrier3

    yv0 = beffv; yv1 = beffv; yv2 = beffv; yv3 = beffv;
#pragma unroll
    for (int w8 = 0; w8 < 8; ++w8) {
      yv0 += redp[0][w8]; yv1 += redp[1][w8];
      yv2 += redp[2][w8]; yv3 += redp[3][w8];
    }
    if (t == 0) out[(row0 + 0) * T_TOT + s] = yv0;
    else if (t == 1) out[(row0 + 1) * T_TOT + s] = yv1;
    else if (t == 2) out[(row0 + 2) * T_TOT + s] = yv2;
    else if (t == 3) out[(row0 + 3) * T_TOT + s] = yv3;
    // no barrier needed here: h/redp hazards are covered by barriers 1-3 of
    // the next step (writers of redp come after barrier2 of step s+1... and
    // redp is rewritten only in P3(s+1), after barriers 1 and 2).
  }
#undef KRED4
}

// ---- launch ---------------------------------------------------------------
extern "C" void kernel_launch(void* const* d_in, const int* in_sizes, int n_in,
                              void* d_out, int out_size, void* d_ws, size_t ws_size,
                              hipStream_t stream) {
  const float* input = (const float*)d_in[0];
  const float* Wih1 = (const float*)d_in[2];
  const float* Whh1 = (const float*)d_in[3];
  const float* bih1 = (const float*)d_in[4];
  const float* bhh1 = (const float*)d_in[5];
  const float* Wih2 = (const float*)d_in[6];
  const float* Whh2 = (const float*)d_in[7];
  const float* bih2 = (const float*)d_in[8];
  const float* bhh2 = (const float*)d_in[9];
  const float* Wih3 = (const float*)d_in[10];
  const float* Whh3 = (const float*)d_in[11];
  const float* bih3 = (const float*)d_in[12];
  const float* bhh3 = (const float*)d_in[13];
  const float* in_proj_w = (const float*)d_in[14];
  const float* in_proj_b = (const float*)d_in[15];
  const float* out_w = (const float*)d_in[16];
  const float* out_b = (const float*)d_in[17];
  const float* lin_w = (const float*)d_in[18];
  const float* lin_b = (const float*)d_in[19];

  char* ws = (char*)d_ws;
  u32* WS = (u32*)(ws + 0);                    // 640 KB unified stream
  float* consG = (float*)(ws + (640 << 10));   // ~8.7 KB

  pack_ws<<<640, 256, 0, stream>>>(WS, Whh1, Wih2, Whh2, Wih3, Whh3);
  prep_cons<<<8, 256, 0, stream>>>(consG, bih1, bhh1, bih2, bhh2, bih3, bhh3, Wih1);
  head_fold<<<1, 128, 0, stream>>>(consG, lin_w, out_w,
                                   in_proj_w + 2 * 128 * 128, in_proj_b + 256,
                                   out_b, lin_b);

  pendulum_persist<<<NBLK, 512, 0, stream>>>(
      input, (const uint4*)WS, consG, (float*)d_out);
}

// Round 16
// 9260.004 us; speedup vs baseline: 3.2753x; 1.7259x over previous
//
#include <hip/hip_runtime.h>

// Pendulum 3-layer LSTM (H=128), B=256 rows, 1024 sequential steps.
// Head collapsed to y = weff.h3 + beff (exact fp32 precompute).
// 128 blocks x 512 threads, 2 rows/block. Thread = (idx in 128, kq in 4).
//
// ROUND 16 = ROUND 9 (champion, 9.07ms) + input-x moved to a 4KB LDS slab.
// Empirical law from rounds 9/11/15: every streamed slot costs ~1 L2 latency
// per wave (no source-level pipelining); round 9's 64-slot structure (L1
// LDS-resident) is the slot-count floor. Remaining inefficiency = ~6 dwords
// of scratch spill per step (demand ~134 vs hard 128 cap). The x-slab removes
// the hot loop's only non-ring global loads + their 64-bit address regs.
//   - L1 weights (128KB) LDS-resident, stream-order w1s[q*512+t].
//   - L2+L3 weights (512KB, L2-resident) via 8-slot register ring, 64-slot
//     consumption-order stream (8 | 64: ring position invariant holds).
//   - 3-barrier cross-step software pipeline (verified rounds 5-9).

typedef _Float16 f16;
typedef _Float16 f16x2 __attribute__((ext_vector_type(2)));
typedef unsigned int u32;

#define T_IN 512
#define T_TOT 1024
#define NBLK 128

__device__ __forceinline__ f16x2 u2h(u32 u) { return __builtin_bit_cast(f16x2, u); }

__device__ __forceinline__ float fdot2f(f16x2 a, f16x2 b, float c) {
#if __has_builtin(__builtin_amdgcn_fdot2)
  return __builtin_amdgcn_fdot2(a, b, c, false);
#else
  return c + (float)a[0] * (float)b[0] + (float)a[1] * (float)b[1];
#endif
}

__device__ __forceinline__ float frcp(float x) {
#if __has_builtin(__builtin_amdgcn_rcpf)
  return __builtin_amdgcn_rcpf(x);
#else
  return 1.f / x;
#endif
}
__device__ __forceinline__ float fsigm(float x) { return frcp(1.f + __expf(-x)); }
__device__ __forceinline__ float ftanh(float x) { return 1.f - 2.f * frcp(1.f + __expf(2.f * x)); }

#define DOT4(acc, w, hv)                     \
  do {                                       \
    f16x2 _h = u2h(hv);                      \
    acc[0] = fdot2f(u2h((w).x), _h, acc[0]); \
    acc[1] = fdot2f(u2h((w).y), _h, acc[1]); \
    acc[2] = fdot2f(u2h((w).z), _h, acc[2]); \
    acc[3] = fdot2f(u2h((w).w), _h, acc[3]); \
  } while (0)

// ---- weight packing -------------------------------------------------------
// Combined L2+L3 stream, consumption order. 64 slots x 512 thread-cols x u4.
// Thread col t = idx*4+kq. Slot map:
//  s<48 (P_A, q=s/6, rmd=s%6):
//    rmd<4:  L2 pair p = kq*32 + 4q + rmd over [Wih2|Whh2] (K=[h1_new|h2_old])
//    rmd>=4: L3-early pair i = 2q+(rmd-4); Whh3 col pair kq*16+i (K=h3_old)
//  s>=48:    L3-late  pair u = s-48;      Wih3 col pair kq*16+u (K=h2_new)
// u4 slot g holds half2{ W[g*128+idx][2p], W[g*128+idx][2p+1] }.
__global__ void pack_stream(u32* dst, const float* Wih2, const float* Whh2,
                            const float* Wih3, const float* Whh3) {
  int tid = blockIdx.x * 256 + threadIdx.x;
  if (tid >= 64 * 512 * 4) return;
  int g = tid & 3;
  int t = (tid >> 2) & 511;
  int s = tid >> 11;
  int idx = t >> 2, kq = t & 3;
  const float* src;
  int p;
  if (s < 48) {
    int q = s / 6, rmd = s % 6;
    if (rmd < 4) {
      p = kq * 32 + 4 * q + rmd;
      if (p < 64) { src = Wih2; } else { src = Whh2; p -= 64; }
    } else {
      p = kq * 16 + 2 * q + (rmd - 4);
      src = Whh3;
    }
  } else {
    p = kq * 16 + (s - 48);
    src = Wih3;
  }
  int j = g * 128 + idx;
  union { f16 h[2]; u32 u; } cv;
  cv.h[0] = (f16)src[j * 128 + 2 * p];
  cv.h[1] = (f16)src[j * 128 + 2 * p + 1];
  dst[tid] = cv.u;
}

// L1 (Whh1), stream order: w1s[q*512 + t], q in [0,16): pair p = kq*16+q.
__global__ void pack1s(u32* dst, const float* Whh1) {
  int tid = blockIdx.x * 256 + threadIdx.x;
  if (tid >= 16 * 512 * 4) return;
  int g = tid & 3;
  int t = (tid >> 2) & 511;
  int q = tid >> 11;
  int idx = t >> 2, kq = t & 3;
  int p = kq * 16 + q;
  int j = g * 128 + idx;
  union { f16 h[2]; u32 u; } cv;
  cv.h[0] = (f16)Whh1[j * 128 + 2 * p];
  cv.h[1] = (f16)Whh1[j * 128 + 2 * p + 1];
  dst[tid] = cv.u;
}

// consT[gg*512 + g*128 + idx]: gg 0=b1,1=b2,2=b3,3=wih1. [2048+idx]=weff, [2176]=beff.
__global__ void prep_cons(float* cons, const float* a1, const float* b1,
                          const float* a2, const float* b2,
                          const float* a3, const float* b3, const float* wih1) {
  int tid = blockIdx.x * 256 + threadIdx.x;
  if (tid >= 2048) return;
  int gg = tid >> 9, g = (tid >> 7) & 3, idx = tid & 127;
  int j = g * 128 + idx;
  float v;
  if (gg == 0) v = a1[j] + b1[j];
  else if (gg == 1) v = a2[j] + b2[j];
  else if (gg == 2) v = a3[j] + b3[j];
  else v = wih1[j];
  cons[tid] = v;
}

__global__ void head_fold(float* cons, const float* lin_w, const float* out_w,
                          const float* Wv, const float* bv,
                          const float* out_b, const float* lin_b) {
  __shared__ float wlo[128];
  __shared__ float pr[128];
  int j = threadIdx.x;
  float s = 0.f;
  for (int k = 0; k < 128; ++k) s += lin_w[k] * out_w[k * 128 + j];
  wlo[j] = s;
  __syncthreads();
  float t = 0.f;
  for (int k = 0; k < 128; ++k) t += wlo[k] * Wv[k * 128 + j];
  cons[2048 + j] = t;
  pr[j] = s * bv[j] + lin_w[j] * out_b[j];
  __syncthreads();
  if (j == 0) {
    float b = lin_b[0];
    for (int k = 0; k < 128; ++k) b += pr[k];
    cons[2176] = b;
  }
}

// ---- main persistent kernel ----------------------------------------------
__global__ __launch_bounds__(512)
__attribute__((amdgpu_waves_per_eu(2))) void pendulum_persist(
    const float* __restrict__ input, const uint4* __restrict__ WT1s,
    const uint4* __restrict__ WS, const float* __restrict__ consG,
    float* __restrict__ out) {
  __shared__ __align__(16) uint4 w1s[8192];     // 128 KB, stream-order L1
  __shared__ __align__(16) f16 h1b[2][2][128];  // [parity][row][idx]
  __shared__ __align__(16) f16 h2b[2][2][128];
  __shared__ __align__(16) f16 h3b[2][128];     // [row][idx], single buffer
  __shared__ float xin[2][T_IN];                // 4 KB input slab (round 16)
  __shared__ float consL[2180];
  __shared__ float redp[2][8];

  const int t = threadIdx.x;
  const int idx = t >> 2;
  const int kq = t & 3;
  const int row0 = blockIdx.x * 2, row1 = row0 + 1;

  for (int e = t; e < 8192; e += 512) w1s[e] = WT1s[e];
  for (int e = t; e < 2177; e += 512) consL[e] = consG[e];
  for (int e = t; e < 1024; e += 512)
    xin[e >> 9][e & 511] = input[(row0 + (e >> 9)) * T_IN + (e & 511)];
  if (t < 128) {
    h1b[0][0][t] = (f16)0.f; h1b[0][1][t] = (f16)0.f;
    h1b[1][0][t] = (f16)0.f; h1b[1][1][t] = (f16)0.f;
    h2b[0][0][t] = (f16)0.f; h2b[0][1][t] = (f16)0.f;
    h2b[1][0][t] = (f16)0.f; h2b[1][1][t] = (f16)0.f;
    h3b[0][t] = (f16)0.f;    h3b[1][t] = (f16)0.f;
  }

  const uint4* Wp = WS + t;
  const uint4* w1p = w1s + t;

  float c1a = 0.f, c1b = 0.f, c2a = 0.f, c2b = 0.f, c3a = 0.f, c3b = 0.f;
  float y0 = 0.f, y1 = 0.f;
  __syncthreads();
  const float beffv = consL[2176];

  // prologue: step-0 layer1 (h1_old = 0 -> no dots)
  {
    float x0 = xin[0][0], x1 = xin[1][0];
    if (kq == 0) {
      float b0 = consL[idx], b2v = consL[256 + idx], b3v = consL[384 + idx];
      float w0 = consL[1536 + idx], w2w = consL[1792 + idx],
            w3w = consL[1920 + idx];
      {
        float ig = fsigm(b0 + x0 * w0);
        float gg = ftanh(b2v + x0 * w2w), og = fsigm(b3v + x0 * w3w);
        c1a = ig * gg; h1b[0][0][idx] = (f16)(og * ftanh(c1a));
      }
      {
        float ig = fsigm(b0 + x1 * w0);
        float gg = ftanh(b2v + x1 * w2w), og = fsigm(b3v + x1 * w3w);
        c1b = ig * gg; h1b[0][1][idx] = (f16)(og * ftanh(c1b));
      }
    }
    __syncthreads();
  }

  // ring prologue: slots 0..7 of the 64-slot per-step stream
  uint4 ring[8];
#pragma unroll
  for (int c = 0; c < 8; ++c) ring[c] = Wp[c * 512];

  for (int s = 0; s < T_TOT; ++s) {
    const int par = s & 1;
    const int xi = (s + 1 < T_IN) ? (s + 1) : 0;
    float xl0 = xin[0][xi];
    float xl1 = xin[1][xi];

    const uint4* hL2r0 = (kq < 2)
        ? (const uint4*)&h1b[par][0][0] + kq * 8
        : (const uint4*)&h2b[par ^ 1][0][0] + (kq - 2) * 8;
    const uint4* hL2r1 = (kq < 2)
        ? (const uint4*)&h1b[par][1][0] + kq * 8
        : (const uint4*)&h2b[par ^ 1][1][0] + (kq - 2) * 8;
    const uint4* h3r0 = (const uint4*)&h3b[0][0] + kq * 4;
    const uint4* h3r1 = (const uint4*)&h3b[1][0] + kq * 4;

    float a2r0[4] = {0, 0, 0, 0}, a2r1[4] = {0, 0, 0, 0};
    float a3r0[4] = {0, 0, 0, 0}, a3r1[4] = {0, 0, 0, 0};

    // ---- P_A: L2 dots (32 u4, ring) + L3-early dots (16 u4, ring) ----
    uint4 E0, E1;
#pragma unroll
    for (int q = 0; q < 8; ++q) {
      uint4 H0 = hL2r0[q], H1 = hL2r1[q];
      u32 e0[4] = {H0.x, H0.y, H0.z, H0.w};
      u32 e1[4] = {H1.x, H1.y, H1.z, H1.w};
      if ((q & 1) == 0) { E0 = h3r0[q >> 1]; E1 = h3r1[q >> 1]; }
#pragma unroll
      for (int m = 0; m < 4; ++m) {
        const int sl = 6 * q + m;  // compile-time slot
        uint4 w = ring[sl & 7];
        ring[sl & 7] = Wp[((sl + 8) & 63) * 512];
        DOT4(a2r0, w, e0[m]);
        DOT4(a2r1, w, e1[m]);
      }
      {
        const int sl = 6 * q + 4;
        uint4 w = ring[sl & 7];
        ring[sl & 7] = Wp[((sl + 8) & 63) * 512];
        u32 h0 = (q & 1) ? E0.z : E0.x, h1v = (q & 1) ? E1.z : E1.x;
        DOT4(a3r0, w, h0);
        DOT4(a3r1, w, h1v);
      }
      {
        const int sl = 6 * q + 5;
        uint4 w = ring[sl & 7];
        ring[sl & 7] = Wp[((sl + 8) & 63) * 512];
        u32 h0 = (q & 1) ? E0.w : E0.y, h1v = (q & 1) ? E1.w : E1.y;
        DOT4(a3r0, w, h0);
        DOT4(a3r1, w, h1v);
      }
    }

    // L2 finish
#pragma unroll
    for (int g = 0; g < 4; ++g) {
      a2r0[g] += __shfl_xor(a2r0[g], 1, 64); a2r0[g] += __shfl_xor(a2r0[g], 2, 64);
      a2r1[g] += __shfl_xor(a2r1[g], 1, 64); a2r1[g] += __shfl_xor(a2r1[g], 2, 64);
    }
    if (kq == 0) {
      float b0 = consL[512 + idx], b1v = consL[640 + idx],
            b2v = consL[768 + idx], b3v = consL[896 + idx];
      {
        float ig = fsigm(a2r0[0] + b0), fg = fsigm(a2r0[1] + b1v);
        float gg = ftanh(a2r0[2] + b2v), og = fsigm(a2r0[3] + b3v);
        c2a = fg * c2a + ig * gg;
        h2b[par][0][idx] = (f16)(og * ftanh(c2a));
      }
      {
        float ig = fsigm(a2r1[0] + b0), fg = fsigm(a2r1[1] + b1v);
        float gg = ftanh(a2r1[2] + b2v), og = fsigm(a2r1[3] + b3v);
        c2b = fg * c2b + ig * gg;
        h2b[par][1][idx] = (f16)(og * ftanh(c2b));
      }
    }
    asm volatile("s_waitcnt lgkmcnt(0)\n\ts_barrier" ::: "memory");  // barrier1

    // ---- P_B: L3-late dots (16 u4, ring) + L1 dots for step s+1 (16 u4, LDS) ----
    const uint4* hLTr0 = (const uint4*)&h2b[par][0][0] + kq * 4;
    const uint4* hLTr1 = (const uint4*)&h2b[par][1][0] + kq * 4;
    const uint4* h1r0 = (const uint4*)&h1b[par][0][0] + kq * 4;
    const uint4* h1r1 = (const uint4*)&h1b[par][1][0] + kq * 4;

    float a1r0[4] = {0, 0, 0, 0}, a1r1[4] = {0, 0, 0, 0};
    uint4 L0, L1v, F0, F1;
#pragma unroll
    for (int q = 0; q < 8; ++q) {
      if ((q & 1) == 0) {
        L0 = hLTr0[q >> 1]; L1v = hLTr1[q >> 1];
        F0 = h1r0[q >> 1];  F1 = h1r1[q >> 1];
      }
      {
        const int sl = 48 + 2 * q;
        uint4 w = ring[sl & 7];
        ring[sl & 7] = Wp[((sl + 8) & 63) * 512];
        u32 h0 = (q & 1) ? L0.z : L0.x, h1x = (q & 1) ? L1v.z : L1v.x;
        DOT4(a3r0, w, h0);
        DOT4(a3r1, w, h1x);
      }
      {
        const int sl = 48 + 2 * q + 1;
        uint4 w = ring[sl & 7];
        ring[sl & 7] = Wp[((sl + 8) & 63) * 512];
        u32 h0 = (q & 1) ? L0.w : L0.y, h1x = (q & 1) ? L1v.w : L1v.y;
        DOT4(a3r0, w, h0);
        DOT4(a3r1, w, h1x);
      }
      {
        uint4 w = w1p[(2 * q) * 512];
        u32 h0 = (q & 1) ? F0.z : F0.x, h1x = (q & 1) ? F1.z : F1.x;
        DOT4(a1r0, w, h0);
        DOT4(a1r1, w, h1x);
      }
      {
        uint4 w = w1p[(2 * q + 1) * 512];
        u32 h0 = (q & 1) ? F0.w : F0.y, h1x = (q & 1) ? F1.w : F1.y;
        DOT4(a1r0, w, h0);
        DOT4(a1r1, w, h1x);
      }
    }

#pragma unroll
    for (int g = 0; g < 4; ++g) {
      a3r0[g] += __shfl_xor(a3r0[g], 1, 64); a3r0[g] += __shfl_xor(a3r0[g], 2, 64);
      a3r1[g] += __shfl_xor(a3r1[g], 1, 64); a3r1[g] += __shfl_xor(a3r1[g], 2, 64);
      a1r0[g] += __shfl_xor(a1r0[g], 1, 64); a1r0[g] += __shfl_xor(a1r0[g], 2, 64);
      a1r1[g] += __shfl_xor(a1r1[g], 1, 64); a1r1[g] += __shfl_xor(a1r1[g], 2, 64);
    }

    // L3 finish + head partial
    float p0 = 0.f, p1 = 0.f;
    if (kq == 0) {
      float b0 = consL[1024 + idx], b1v = consL[1152 + idx],
            b2v = consL[1280 + idx], b3v = consL[1408 + idx];
      float weffr = consL[2048 + idx];
      {
        float ig = fsigm(a3r0[0] + b0), fg = fsigm(a3r0[1] + b1v);
        float gg = ftanh(a3r0[2] + b2v), og = fsigm(a3r0[3] + b3v);
        c3a = fg * c3a + ig * gg;
        float h3 = og * ftanh(c3a);
        h3b[0][idx] = (f16)h3;
        p0 = weffr * h3;
      }
      {
        float ig = fsigm(a3r1[0] + b0), fg = fsigm(a3r1[1] + b1v);
        float gg = ftanh(a3r1[2] + b2v), og = fsigm(a3r1[3] + b3v);
        c3b = fg * c3b + ig * gg;
        float h3 = og * ftanh(c3b);
        h3b[1][idx] = (f16)h3;
        p1 = weffr * h3;
      }
    }
#pragma unroll
    for (int k = 1; k < 64; k <<= 1) {
      p0 += __shfl_xor(p0, k, 64);
      p1 += __shfl_xor(p1, k, 64);
    }
    if ((t & 63) == 0) { redp[0][t >> 6] = p0; redp[1][t >> 6] = p1; }
    asm volatile("s_waitcnt lgkmcnt(0)\n\ts_barrier" ::: "memory");  // barrier2

    y0 = beffv; y1 = beffv;
#pragma unroll
    for (int w8 = 0; w8 < 8; ++w8) { y0 += redp[0][w8]; y1 += redp[1][w8]; }
    if (t == 0) out[row0 * T_TOT + s] = y0;
    else if (t == 1) out[row1 * T_TOT + s] = y1;

    // L1 finish for step s+1
    float xv0 = (s + 1 < T_IN) ? xl0 : y0;
    float xv1 = (s + 1 < T_IN) ? xl1 : y1;
    if (kq == 0) {
      float b0 = consL[idx], b1v = consL[128 + idx], b2v = consL[256 + idx],
            b3v = consL[384 + idx];
      float w0 = consL[1536 + idx], w1w = consL[1664 + idx],
            w2w = consL[1792 + idx], w3w = consL[1920 + idx];
      {
        float ig = fsigm(a1r0[0] + b0 + xv0 * w0), fg = fsigm(a1r0[1] + b1v + xv0 * w1w);
        float gg = ftanh(a1r0[2] + b2v + xv0 * w2w), og = fsigm(a1r0[3] + b3v + xv0 * w3w);
        c1a = fg * c1a + ig * gg;
        h1b[par ^ 1][0][idx] = (f16)(og * ftanh(c1a));
      }
      {
        float ig = fsigm(a1r1[0] + b0 + xv1 * w0), fg = fsigm(a1r1[1] + b1v + xv1 * w1w);
        float gg = ftanh(a1r1[2] + b2v + xv1 * w2w), og = fsigm(a1r1[3] + b3v + xv1 * w3w);
        c1b = fg * c1b + ig * gg;
        h1b[par ^ 1][1][idx] = (f16)(og * ftanh(c1b));
      }
    }
    asm volatile("s_waitcnt lgkmcnt(0)\n\ts_barrier" ::: "memory");  // barrier3
  }
}

// ---- launch ---------------------------------------------------------------
extern "C" void kernel_launch(void* const* d_in, const int* in_sizes, int n_in,
                              void* d_out, int out_size, void* d_ws, size_t ws_size,
                              hipStream_t stream) {
  const float* input = (const float*)d_in[0];
  const float* Wih1 = (const float*)d_in[2];
  const float* Whh1 = (const float*)d_in[3];
  const float* bih1 = (const float*)d_in[4];
  const float* bhh1 = (const float*)d_in[5];
  const float* Wih2 = (const float*)d_in[6];
  const float* Whh2 = (const float*)d_in[7];
  const float* bih2 = (const float*)d_in[8];
  const float* bhh2 = (const float*)d_in[9];
  const float* Wih3 = (const float*)d_in[10];
  const float* Whh3 = (const float*)d_in[11];
  const float* bih3 = (const float*)d_in[12];
  const float* bhh3 = (const float*)d_in[13];
  const float* in_proj_w = (const float*)d_in[14];
  const float* in_proj_b = (const float*)d_in[15];
  const float* out_w = (const float*)d_in[16];
  const float* out_b = (const float*)d_in[17];
  const float* lin_w = (const float*)d_in[18];
  const float* lin_b = (const float*)d_in[19];

  char* ws = (char*)d_ws;
  u32* WT1s = (u32*)(ws + (0 << 10));   // 128 KB stream-order L1
  u32* WS = (u32*)(ws + (128 << 10));   // 512 KB combined L2+L3 stream
  float* consG = (float*)(ws + (640 << 10));  // ~8.7 KB

  pack1s<<<128, 256, 0, stream>>>(WT1s, Whh1);
  pack_stream<<<512, 256, 0, stream>>>(WS, Wih2, Whh2, Wih3, Whh3);
  prep_cons<<<8, 256, 0, stream>>>(consG, bih1, bhh1, bih2, bhh2, bih3, bhh3, Wih1);
  head_fold<<<1, 128, 0, stream>>>(consG, lin_w, out_w,
                                   in_proj_w + 2 * 128 * 128, in_proj_b + 256,
                                   out_b, lin_b);

  pendulum_persist<<<NBLK, 512, 0, stream>>>(
      input, (const uint4*)WT1s, (const uint4*)WS, consG, (float*)d_out);
}